// Round 2
// baseline (1007.816 us; speedup 1.0000x reference)
//
#include <hip/hip_runtime.h>

// Problem constants (from reference setup_inputs)
#define NDOCS 64
#define SS    512            // sentences per doc
#define FIN   256            // HIDDEN (input features)
#define NH    4              // heads
#define DD    256            // per-head out feats
#define NTOT  (NDOCS*SS)     // 32768 rows
#define HF    (NH*DD)        // 1024
#define NEG   0.2f

// ---------------------------------------------------------------------------
// Kernel 1: h = X @ W  (32768x256 @ 256x1024), f32, fused el/er epilogue.
// Block tile: 64 rows x 256 cols (one full head). 256 threads, 8x8 per thread.
// Per-thread N-elements strided by 32 so LDS B-reads are bank-conflict-free.
// ---------------------------------------------------------------------------
__global__ __launch_bounds__(256) void k_fc(const float* __restrict__ X,
                                            const float* __restrict__ W,
                                            const float* __restrict__ attn_l,
                                            const float* __restrict__ attn_r,
                                            float* __restrict__ hbuf,
                                            float* __restrict__ el,
                                            float* __restrict__ er) {
    __shared__ float A[16][68];    // [k][m], pad 68 keeps rows 16B-aligned (272B)
    __shared__ float Bt[16][256];  // [k][n]

    const int t    = threadIdx.x;
    const int bx   = blockIdx.x;
    const int mt   = bx >> 2;       // 0..511 row-tile
    const int hh   = bx & 3;        // head == N-tile
    const int row0 = mt * 64;
    const int n0   = hh * 256;
    const int tm   = t >> 5;        // 0..7  (m group)
    const int td   = t & 31;        // 0..31 (n lane)

    float acc[8][8];
#pragma unroll
    for (int i = 0; i < 8; i++)
#pragma unroll
        for (int j = 0; j < 8; j++) acc[i][j] = 0.f;

    const int ai = t >> 2;          // 0..63 tile row for A staging
    const int aj = (t & 3) * 4;     // k quad for A staging
    const int wj = t >> 6;          // 0..3 base row for B staging
    const int wc = (t & 63) * 4;    // col quad for B staging

    for (int k0 = 0; k0 < FIN; k0 += 16) {
        // stage A: X tile 64x16 -> A[k][m]
        float4 av = *reinterpret_cast<const float4*>(X + (size_t)(row0 + ai) * FIN + k0 + aj);
        A[aj + 0][ai] = av.x;
        A[aj + 1][ai] = av.y;
        A[aj + 2][ai] = av.z;
        A[aj + 3][ai] = av.w;
        // stage B: W tile 16x256 -> Bt[k][n]
#pragma unroll
        for (int r = 0; r < 4; r++) {
            int jj = wj + r * 4;
            *reinterpret_cast<float4*>(&Bt[jj][wc]) =
                *reinterpret_cast<const float4*>(W + (size_t)(k0 + jj) * HF + n0 + wc);
        }
        __syncthreads();
#pragma unroll
        for (int k = 0; k < 16; k++) {
            float4 a0 = *reinterpret_cast<const float4*>(&A[k][tm * 8]);
            float4 a1 = *reinterpret_cast<const float4*>(&A[k][tm * 8 + 4]);
            float am[8] = {a0.x, a0.y, a0.z, a0.w, a1.x, a1.y, a1.z, a1.w};
            float bv[8];
#pragma unroll
            for (int ni = 0; ni < 8; ni++) bv[ni] = Bt[k][td + 32 * ni];
#pragma unroll
            for (int mi = 0; mi < 8; mi++)
#pragma unroll
                for (int ni = 0; ni < 8; ni++)
                    acc[mi][ni] = fmaf(am[mi], bv[ni], acc[mi][ni]);
        }
        __syncthreads();
    }

    // Epilogue: write h, reduce el/er per row (this block owns a full head).
    float al[8], ar[8];
#pragma unroll
    for (int ni = 0; ni < 8; ni++) {
        al[ni] = attn_l[n0 + td + 32 * ni];
        ar[ni] = attn_r[n0 + td + 32 * ni];
    }
#pragma unroll
    for (int mi = 0; mi < 8; mi++) {
        int row = row0 + tm * 8 + mi;
        float pl = 0.f, pr = 0.f;
#pragma unroll
        for (int ni = 0; ni < 8; ni++) {
            float v = acc[mi][ni];
            hbuf[(size_t)row * HF + n0 + td + 32 * ni] = v;
            pl = fmaf(v, al[ni], pl);
            pr = fmaf(v, ar[ni], pr);
        }
        // reduce across the 32 lanes sharing this row (xor offsets stay in-group)
#pragma unroll
        for (int off = 16; off >= 1; off >>= 1) {
            pl += __shfl_xor(pl, off);
            pr += __shfl_xor(pr, off);
        }
        if (td == 0) {
            el[hh * NTOT + row] = pl;
            er[hh * NTOT + row] = pr;
        }
    }
}

// ---------------------------------------------------------------------------
// Kernel 2: per (doc, 64-dst tile): loop heads, softmax over src, aggregate
// out[dst,d] += alpha^T h, accumulate across heads, write 0.25*(acc+bias_sum).
// ---------------------------------------------------------------------------
__global__ __launch_bounds__(256) void k_attn(const float* __restrict__ hbuf,
                                              const float* __restrict__ el,
                                              const float* __restrict__ er,
                                              const float* __restrict__ bias,
                                              float* __restrict__ out) {
    __shared__ float els[SS];
    __shared__ float ers[64];
    __shared__ float ms[64];
    __shared__ float rden[64];
    __shared__ float P[16][64];     // [k][dst]
    __shared__ float hs[16][256];   // [k][d]

    const int t    = threadIdx.x;
    const int b    = blockIdx.x >> 3;
    const int tile = blockIdx.x & 7;
    const int dst0 = tile * 64;
    const int tm   = t >> 5;        // dst group (8 dsts)
    const int td   = t & 31;        // d lane

    float acc[8][8];
#pragma unroll
    for (int i = 0; i < 8; i++)
#pragma unroll
        for (int j = 0; j < 8; j++) acc[i][j] = 0.f;

    float bsum[8];
#pragma unroll
    for (int ni = 0; ni < 8; ni++) {
        float s = 0.f;
        for (int h = 0; h < NH; h++) s += bias[h * 256 + td + 32 * ni];
        bsum[ni] = s;
    }

    const int pj = t >> 6;          // h staging base row
    const int pc = (t & 63) * 4;    // h staging col quad

    for (int hh = 0; hh < NH; hh++) {
        // load el (512) and er (64) for this (doc, head)
        els[t]       = el[hh * NTOT + b * SS + t];
        els[t + 256] = el[hh * NTOT + b * SS + t + 256];
        if (t < 64) ers[t] = er[hh * NTOT + b * SS + dst0 + t];
        __syncthreads();

        // phase B: per dst, max & sum over 512 srcs (4 threads per dst)
        {
            int dd = t >> 2, q = t & 3;
            float erv = ers[dd];
            float mx = -1e30f;
            for (int s0 = q; s0 < SS; s0 += 4) {
                float x = els[s0] + erv;
                x = x > 0.f ? x : NEG * x;
                mx = fmaxf(mx, x);
            }
            mx = fmaxf(mx, __shfl_xor(mx, 1));
            mx = fmaxf(mx, __shfl_xor(mx, 2));
            float sm = 0.f;
            for (int s0 = q; s0 < SS; s0 += 4) {
                float x = els[s0] + erv;
                x = x > 0.f ? x : NEG * x;
                sm += __expf(x - mx);
            }
            sm += __shfl_xor(sm, 1);
            sm += __shfl_xor(sm, 2);
            if (q == 0) { ms[dd] = mx; rden[dd] = 1.f / sm; }
        }
        __syncthreads();

        // phase C: K-loop over srcs in chunks of 16
        for (int kc = 0; kc < SS; kc += 16) {
            // stage P chunk: entry id = 4t+i -> (k = id>>6, dst = id&63)
            {
                int k  = (4 * t) >> 6;
                int d0 = (4 * t) & 63;
                float ev = els[kc + k];
#pragma unroll
                for (int i = 0; i < 4; i++) {
                    int ddx = d0 + i;
                    float x = ev + ers[ddx];
                    x = x > 0.f ? x : NEG * x;
                    P[k][ddx] = __expf(x - ms[ddx]) * rden[ddx];
                }
            }
            // stage h chunk 16x256
#pragma unroll
            for (int r = 0; r < 4; r++) {
                int jj = pj + r * 4;
                *reinterpret_cast<float4*>(&hs[jj][pc]) =
                    *reinterpret_cast<const float4*>(
                        hbuf + (size_t)(b * SS + kc + jj) * HF + hh * 256 + pc);
            }
            __syncthreads();
#pragma unroll
            for (int k = 0; k < 16; k++) {
                float4 p0 = *reinterpret_cast<const float4*>(&P[k][tm * 8]);
                float4 p1 = *reinterpret_cast<const float4*>(&P[k][tm * 8 + 4]);
                float pm[8] = {p0.x, p0.y, p0.z, p0.w, p1.x, p1.y, p1.z, p1.w};
                float hv[8];
#pragma unroll
                for (int ni = 0; ni < 8; ni++) hv[ni] = hs[k][td + 32 * ni];
#pragma unroll
                for (int mi = 0; mi < 8; mi++)
#pragma unroll
                    for (int ni = 0; ni < 8; ni++)
                        acc[mi][ni] = fmaf(pm[mi], hv[ni], acc[mi][ni]);
            }
            __syncthreads();
        }
    }

    // epilogue: final = 0.25 * (sum_h out_h + sum_h bias_h)
#pragma unroll
    for (int mi = 0; mi < 8; mi++) {
        int row = b * SS + dst0 + tm * 8 + mi;
#pragma unroll
        for (int ni = 0; ni < 8; ni++) {
            out[(size_t)row * DD + td + 32 * ni] = 0.25f * (acc[mi][ni] + bsum[ni]);
        }
    }
}

// ---------------------------------------------------------------------------
extern "C" void kernel_launch(void* const* d_in, const int* in_sizes, int n_in,
                              void* d_out, int out_size, void* d_ws, size_t ws_size,
                              hipStream_t stream) {
    const float* X      = (const float*)d_in[0];  // sent_feature [32768,256]
    const float* W      = (const float*)d_in[1];  // [256,1024]
    const float* attn_l = (const float*)d_in[2];  // [4,256]
    const float* attn_r = (const float*)d_in[3];  // [4,256]
    const float* bias   = (const float*)d_in[4];  // [1024]
    // d_in[5] = num_docs (constant 64, baked in)

    float* ws   = (float*)d_ws;
    float* hbuf = ws;                                   // 32768*1024 f32 = 128 MiB
    float* elp  = ws + (size_t)NTOT * HF;               // 4*32768 f32
    float* erp  = elp + (size_t)NH * NTOT;              // 4*32768 f32
    float* outp = (float*)d_out;

    k_fc<<<2048, 256, 0, stream>>>(X, W, attn_l, attn_r, hbuf, elp, erp);
    k_attn<<<NDOCS * 8, 256, 0, stream>>>(hbuf, elp, erp, bias, outp);
}

// Round 3
// 464.473 us; speedup vs baseline: 2.1698x; 2.1698x over previous
//
#include <hip/hip_runtime.h>
#include <hip/hip_bf16.h>

// Problem constants (from reference setup_inputs)
#define NDOCS 64
#define SS    512            // sentences per doc
#define FIN   256            // HIDDEN (input features)
#define NH    4              // heads
#define DD    256            // per-head out feats
#define NTOT  (NDOCS*SS)     // 32768 rows
#define HF    (NH*DD)        // 1024
#define NEG   0.2f

typedef __attribute__((ext_vector_type(8))) short bf16x8;   // 8 bf16 = 4 VGPRs
typedef __attribute__((ext_vector_type(4))) float f32x4;    // MFMA 16x16 acc

__device__ __forceinline__ unsigned short f2b(float x) {
    __hip_bfloat16 b = __float2bfloat16(x);
    return *reinterpret_cast<unsigned short*>(&b);
}

// ---------------------------------------------------------------------------
// Kernel 1: h = X @ W (f32 vector GEMM, unchanged main loop).
// Epilogue: el/er from exact f32 accs; h stored TRANSPOSED bf16 hT[b][h][d][s].
// Thread (tm,td) holds 8 consecutive src rows per column -> 1 b128 store each.
// ---------------------------------------------------------------------------
__global__ __launch_bounds__(256) void k_fc(const float* __restrict__ X,
                                            const float* __restrict__ W,
                                            const float* __restrict__ attn_l,
                                            const float* __restrict__ attn_r,
                                            unsigned short* __restrict__ hT,
                                            float* __restrict__ el,
                                            float* __restrict__ er) {
    __shared__ float A[16][68];    // [k][m]
    __shared__ float Bt[16][256];  // [k][n]

    const int t    = threadIdx.x;
    const int bx   = blockIdx.x;
    const int mt   = bx >> 2;       // 0..511 row-tile
    const int hh   = bx & 3;        // head == N-tile
    const int row0 = mt * 64;
    const int n0   = hh * 256;
    const int tm   = t >> 5;        // 0..7  (m group)
    const int td   = t & 31;        // 0..31 (n lane)

    float acc[8][8];
#pragma unroll
    for (int i = 0; i < 8; i++)
#pragma unroll
        for (int j = 0; j < 8; j++) acc[i][j] = 0.f;

    const int ai = t >> 2;          // 0..63 tile row for A staging
    const int aj = (t & 3) * 4;     // k quad for A staging
    const int wj = t >> 6;          // 0..3 base row for B staging
    const int wc = (t & 63) * 4;    // col quad for B staging

    for (int k0 = 0; k0 < FIN; k0 += 16) {
        float4 av = *reinterpret_cast<const float4*>(X + (size_t)(row0 + ai) * FIN + k0 + aj);
        A[aj + 0][ai] = av.x;
        A[aj + 1][ai] = av.y;
        A[aj + 2][ai] = av.z;
        A[aj + 3][ai] = av.w;
#pragma unroll
        for (int r = 0; r < 4; r++) {
            int jj = wj + r * 4;
            *reinterpret_cast<float4*>(&Bt[jj][wc]) =
                *reinterpret_cast<const float4*>(W + (size_t)(k0 + jj) * HF + n0 + wc);
        }
        __syncthreads();
#pragma unroll
        for (int k = 0; k < 16; k++) {
            float4 a0 = *reinterpret_cast<const float4*>(&A[k][tm * 8]);
            float4 a1 = *reinterpret_cast<const float4*>(&A[k][tm * 8 + 4]);
            float am[8] = {a0.x, a0.y, a0.z, a0.w, a1.x, a1.y, a1.z, a1.w};
            float bv[8];
#pragma unroll
            for (int ni = 0; ni < 8; ni++) bv[ni] = Bt[k][td + 32 * ni];
#pragma unroll
            for (int mi = 0; mi < 8; mi++)
#pragma unroll
                for (int ni = 0; ni < 8; ni++)
                    acc[mi][ni] = fmaf(am[mi], bv[ni], acc[mi][ni]);
        }
        __syncthreads();
    }

    // el/er from exact f32 accumulators (unchanged math)
    float al[8], ar[8];
#pragma unroll
    for (int ni = 0; ni < 8; ni++) {
        al[ni] = attn_l[n0 + td + 32 * ni];
        ar[ni] = attn_r[n0 + td + 32 * ni];
    }
#pragma unroll
    for (int mi = 0; mi < 8; mi++) {
        int row = row0 + tm * 8 + mi;
        float pl = 0.f, pr = 0.f;
#pragma unroll
        for (int ni = 0; ni < 8; ni++) {
            pl = fmaf(acc[mi][ni], al[ni], pl);
            pr = fmaf(acc[mi][ni], ar[ni], pr);
        }
#pragma unroll
        for (int off = 16; off >= 1; off >>= 1) {
            pl += __shfl_xor(pl, off);
            pr += __shfl_xor(pr, off);
        }
        if (td == 0) {
            el[hh * NTOT + row] = pl;
            er[hh * NTOT + row] = pr;
        }
    }

    // hT store: hT[(bdoc*NH+hh)*DD + d][s] bf16, 8 consecutive s per b128
    const int bdoc = row0 >> 9;            // 64-row tiles never straddle docs
    const int sloc = (row0 & 511) + tm * 8;
    unsigned short* hTp = hT + ((size_t)(bdoc * NH + hh) * DD) * SS;
#pragma unroll
    for (int ni = 0; ni < 8; ni++) {
        int d = td + 32 * ni;
        uint4 u;
        u.x = (unsigned)f2b(acc[0][ni]) | ((unsigned)f2b(acc[1][ni]) << 16);
        u.y = (unsigned)f2b(acc[2][ni]) | ((unsigned)f2b(acc[3][ni]) << 16);
        u.z = (unsigned)f2b(acc[4][ni]) | ((unsigned)f2b(acc[5][ni]) << 16);
        u.w = (unsigned)f2b(acc[6][ni]) | ((unsigned)f2b(acc[7][ni]) << 16);
        *reinterpret_cast<uint4*>(hTp + (size_t)d * SS + sloc) = u;
    }
}

// ---------------------------------------------------------------------------
// Kernel 2: MFMA aggregation. Block = (doc, 64-dst tile), 4 waves, heads
// looped in-register. out = P^T(64x512) @ h(512x256) per head, acc f32.
// A = PT[dst][src] (computed bf16), B = HS[d][src] (staged from hT).
// XOR slot swizzle: 16B-slot ^= (row&7) on both write and read sides.
// ---------------------------------------------------------------------------
__global__ __launch_bounds__(256) void k_attn(const unsigned short* __restrict__ hT,
                                              const float* __restrict__ el,
                                              const float* __restrict__ er,
                                              const float* __restrict__ bias,
                                              float* __restrict__ out) {
    __shared__ __align__(16) unsigned short PT[64 * 64];     // 8 KB, [dst][64 src]
    __shared__ __align__(16) unsigned short HS[4][64 * 64];  // 32 KB, per-wave [64 d][64 src]
    __shared__ float els[SS];
    __shared__ float ers[64], ms[64], rden[64];

    const int t    = threadIdx.x;
    const int b    = blockIdx.x >> 3;
    const int tile = blockIdx.x & 7;
    const int dst0 = tile * 64;
    const int w    = t >> 6;        // wave id: owns d range w*64..+63
    const int l    = t & 63;        // lane
    const int lr16 = l & 15;
    const int lg   = l >> 4;        // 0..3

    f32x4 acc[4][4];
#pragma unroll
    for (int mt = 0; mt < 4; mt++)
#pragma unroll
        for (int nt = 0; nt < 4; nt++)
#pragma unroll
            for (int r = 0; r < 4; r++) acc[mt][nt][r] = 0.f;

    for (int hh = 0; hh < NH; hh++) {
        els[t]       = el[hh * NTOT + b * SS + t];
        els[t + 256] = el[hh * NTOT + b * SS + t + 256];
        if (t < 64) ers[t] = er[hh * NTOT + b * SS + dst0 + t];
        __syncthreads();

        // softmax stats per dst (f32, 4 threads per dst) — unchanged
        {
            int dd = t >> 2, q = t & 3;
            float erv = ers[dd];
            float mx = -1e30f;
            for (int s0 = q; s0 < SS; s0 += 4) {
                float x = els[s0] + erv;
                x = x > 0.f ? x : NEG * x;
                mx = fmaxf(mx, x);
            }
            mx = fmaxf(mx, __shfl_xor(mx, 1));
            mx = fmaxf(mx, __shfl_xor(mx, 2));
            float sm = 0.f;
            for (int s0 = q; s0 < SS; s0 += 4) {
                float x = els[s0] + erv;
                x = x > 0.f ? x : NEG * x;
                sm += __expf(x - mx);
            }
            sm += __shfl_xor(sm, 1);
            sm += __shfl_xor(sm, 2);
            if (q == 0) { ms[dd] = mx; rden[dd] = 1.f / sm; }
        }
        __syncthreads();

        const unsigned short* hTw = hT + ((size_t)(b * NH + hh) * DD + w * 64) * SS;

        for (int s0 = 0; s0 < SS; s0 += 64) {
            // ---- stage PT (all 256 threads): thread -> (dst = t&63, 16 srcs)
            {
                int dst = t & 63;
                int sb  = (t >> 6) * 16;
                float erv = ers[dst], m = ms[dst], rd = rden[dst];
                unsigned int wb[8];
#pragma unroll
                for (int jp = 0; jp < 8; jp++) {
                    float x0 = els[s0 + sb + 2 * jp]     + erv; x0 = x0 > 0.f ? x0 : NEG * x0;
                    float x1 = els[s0 + sb + 2 * jp + 1] + erv; x1 = x1 > 0.f ? x1 : NEG * x1;
                    wb[jp] = (unsigned)f2b(__expf(x0 - m) * rd) |
                             ((unsigned)f2b(__expf(x1 - m) * rd) << 16);
                }
                int ds0   = (t >> 6) * 2;                 // data slot of first 8 srcs
                int slot0 = (ds0    ) ^ (dst & 7);
                int slot1 = (ds0 + 1) ^ (dst & 7);
                uint4 u0, u1;
                u0.x = wb[0]; u0.y = wb[1]; u0.z = wb[2]; u0.w = wb[3];
                u1.x = wb[4]; u1.y = wb[5]; u1.z = wb[6]; u1.w = wb[7];
                char* ptb = reinterpret_cast<char*>(PT) + dst * 128;
                *reinterpret_cast<uint4*>(ptb + slot0 * 16) = u0;
                *reinterpret_cast<uint4*>(ptb + slot1 * 16) = u1;
            }
            // ---- stage HS for this wave: 64 d-rows x 64 srcs (bf16 16B chunks)
            {
                int q  = l & 7;      // src slot
                int dl = l >> 3;     // d within 8-row group
                char* hsb = reinterpret_cast<char*>(&HS[w][0]);
#pragma unroll
                for (int r = 0; r < 8; r++) {
                    int d = r * 8 + dl;
                    uint4 v = *reinterpret_cast<const uint4*>(hTw + (size_t)d * SS + s0 + q * 8);
                    *reinterpret_cast<uint4*>(hsb + d * 128 + ((q ^ (d & 7)) * 16)) = v;
                }
            }
            __syncthreads();
            // ---- MFMA: 2 K-steps of 32
#pragma unroll
            for (int ki = 0; ki < 2; ki++) {
                int ds = ki * 4 + lg;   // data slot for this lane's 8 srcs
                bf16x8 af[4], bf[4];
                const char* ptb = reinterpret_cast<const char*>(PT);
                const char* hsb = reinterpret_cast<const char*>(&HS[w][0]);
#pragma unroll
                for (int mt = 0; mt < 4; mt++) {
                    int dst = mt * 16 + lr16;
                    af[mt] = *reinterpret_cast<const bf16x8*>(ptb + dst * 128 + ((ds ^ (dst & 7)) * 16));
                }
#pragma unroll
                for (int nt = 0; nt < 4; nt++) {
                    int d = nt * 16 + lr16;
                    bf[nt] = *reinterpret_cast<const bf16x8*>(hsb + d * 128 + ((ds ^ (d & 7)) * 16));
                }
#pragma unroll
                for (int mt = 0; mt < 4; mt++)
#pragma unroll
                    for (int nt = 0; nt < 4; nt++)
                        acc[mt][nt] = __builtin_amdgcn_mfma_f32_16x16x32_bf16(
                            af[mt], bf[nt], acc[mt][nt], 0, 0, 0);
            }
            __syncthreads();
        }
    }

    // epilogue: out = 0.25*(sum_h acc + sum_h bias); C/D: col=l&15, row=lg*4+reg
    float bs[4];
#pragma unroll
    for (int nt = 0; nt < 4; nt++) {
        int d = w * 64 + nt * 16 + lr16;
        float s = 0.f;
        for (int h2 = 0; h2 < NH; h2++) s += bias[h2 * DD + d];
        bs[nt] = s;
    }
#pragma unroll
    for (int mt = 0; mt < 4; mt++) {
        int rowb = b * SS + dst0 + mt * 16 + lg * 4;
#pragma unroll
        for (int nt = 0; nt < 4; nt++) {
            int d = w * 64 + nt * 16 + lr16;
#pragma unroll
            for (int rg = 0; rg < 4; rg++)
                out[(size_t)(rowb + rg) * DD + d] = 0.25f * (acc[mt][nt][rg] + bs[nt]);
        }
    }
}

// ---------------------------------------------------------------------------
extern "C" void kernel_launch(void* const* d_in, const int* in_sizes, int n_in,
                              void* d_out, int out_size, void* d_ws, size_t ws_size,
                              hipStream_t stream) {
    const float* X      = (const float*)d_in[0];  // sent_feature [32768,256]
    const float* W      = (const float*)d_in[1];  // [256,1024]
    const float* attn_l = (const float*)d_in[2];  // [4,256]
    const float* attn_r = (const float*)d_in[3];  // [4,256]
    const float* bias   = (const float*)d_in[4];  // [1024]
    // d_in[5] = num_docs (constant 64, baked in)

    unsigned short* hT = (unsigned short*)d_ws;                    // 64 MB bf16 hT[b][h][d][s]
    float* elp = (float*)((char*)d_ws + (size_t)NTOT * HF * 2);    // 4*32768 f32
    float* erp = elp + (size_t)NH * NTOT;
    float* outp = (float*)d_out;

    k_fc<<<2048, 256, 0, stream>>>(X, W, attn_l, attn_r, hT, elp, erp);
    k_attn<<<NDOCS * 8, 256, 0, stream>>>(hT, elp, erp, bias, outp);
}

// Round 5
// 320.141 us; speedup vs baseline: 3.1480x; 1.4508x over previous
//
#include <hip/hip_runtime.h>
#include <hip/hip_bf16.h>

// Problem constants (from reference setup_inputs)
#define NDOCS 64
#define SS    512            // sentences per doc
#define FIN   256            // HIDDEN (input features)
#define NH    4              // heads
#define DD    256            // per-head out feats
#define NTOT  (NDOCS*SS)     // 32768 rows
#define HF    (NH*DD)        // 1024
#define NEG   0.2f
#define LDA   264            // Ald row stride in shorts: 256 + 8 pad = 528 B (16B-aligned, bank-shifted)

typedef __attribute__((ext_vector_type(8))) short bf16x8;   // 8 bf16 = 4 VGPRs
typedef __attribute__((ext_vector_type(4))) float f32x4;    // MFMA 16x16 acc

__device__ __forceinline__ unsigned short f2b(float x) {
    __hip_bfloat16 b = __float2bfloat16(x);
    return *reinterpret_cast<unsigned short*>(&b);
}
__device__ __forceinline__ unsigned pk2(float a, float b) {
    return (unsigned)f2b(a) | ((unsigned)f2b(b) << 16);
}

// ---------------------------------------------------------------------------
// Kernel 0: WT[n][k] = bf16(W[k][n])  (1024 x 256, 0.5 MB) — one-time transpose
// ---------------------------------------------------------------------------
__global__ __launch_bounds__(256) void k_wt(const float* __restrict__ W,
                                            unsigned short* __restrict__ WT) {
    int n  = blockIdx.x * 16 + (threadIdx.x & 15);
    int k0 = threadIdx.x >> 4;          // 0..15
#pragma unroll
    for (int i = 0; i < 16; i++) {
        int k = i * 16 + k0;
        WT[(size_t)n * FIN + k] = f2b(W[(size_t)k * HF + n]);
    }
}

// ---------------------------------------------------------------------------
// Kernel 1 (MFMA): h = X @ W. Block = (64-row tile, head): 64 rows x 256 cols.
// A (X) staged full-K in LDS bf16 (padded rows); B-frags straight from global
// WT (L2-resident). One barrier pair total. Epilogue: el/er via shfl+LDS
// reduce from f32 acc; hT stored transposed bf16 [b][h][d][s].
// ---------------------------------------------------------------------------
__global__ __launch_bounds__(256) void k_fc(const float* __restrict__ X,
                                            const unsigned short* __restrict__ WT,
                                            const float* __restrict__ attn_l,
                                            const float* __restrict__ attn_r,
                                            unsigned short* __restrict__ hT,
                                            float* __restrict__ el,
                                            float* __restrict__ er) {
    __shared__ __align__(16) unsigned short Ald[64 * LDA];   // 33 KB
    __shared__ float redl[4][64], redr[4][64];               // 2 KB

    const int t    = threadIdx.x;
    const int mt64 = blockIdx.x >> 2;   // 0..511 row-tile
    const int hh   = blockIdx.x & 3;    // head
    const int row0 = mt64 * 64;
    const int w    = t >> 6;            // wave: owns cols w*64..+63 of this head
    const int l    = t & 63;
    const int lr16 = l & 15;
    const int lg   = l >> 4;

    // ---- stage X[row0..+64][0..256) f32 -> bf16 LDS (perfectly coalesced)
    {
        const int c4   = (t & 63) * 4;  // k col (4 floats per load)
        const int rsub = t >> 6;        // 0..3
#pragma unroll
        for (int i = 0; i < 16; i++) {
            int r = i * 4 + rsub;
            float4 v = *reinterpret_cast<const float4*>(X + (size_t)(row0 + r) * FIN + c4);
            uint2 uu;
            uu.x = pk2(v.x, v.y);
            uu.y = pk2(v.z, v.w);
            *reinterpret_cast<uint2*>(&Ald[r * LDA + c4]) = uu;
        }
    }
    __syncthreads();

    f32x4 acc[4][4];
#pragma unroll
    for (int mt = 0; mt < 4; mt++)
#pragma unroll
        for (int nt = 0; nt < 4; nt++)
#pragma unroll
            for (int rg = 0; rg < 4; rg++) acc[mt][nt][rg] = 0.f;

    const unsigned short* wtb = WT + (size_t)(hh * DD + w * 64) * FIN;

#pragma unroll
    for (int kc = 0; kc < 8; kc++) {    // K = 256 = 8 chunks of 32
        bf16x8 af[4], bv[4];
#pragma unroll
        for (int mt = 0; mt < 4; mt++)
            af[mt] = *reinterpret_cast<const bf16x8*>(
                &Ald[(mt * 16 + lr16) * LDA + kc * 32 + lg * 8]);
#pragma unroll
        for (int nt = 0; nt < 4; nt++)
            bv[nt] = *reinterpret_cast<const bf16x8*>(
                wtb + (size_t)(nt * 16 + lr16) * FIN + kc * 32 + lg * 8);
#pragma unroll
        for (int mt = 0; mt < 4; mt++)
#pragma unroll
            for (int nt = 0; nt < 4; nt++)
                acc[mt][nt] = __builtin_amdgcn_mfma_f32_16x16x32_bf16(
                    af[mt], bv[nt], acc[mt][nt], 0, 0, 0);
    }

    // ---- el/er: partial over this wave's 64 cols, reduce lr16 then cross-wave
    float al4[4], ar4[4];
#pragma unroll
    for (int nt = 0; nt < 4; nt++) {
        int d = w * 64 + nt * 16 + lr16;
        al4[nt] = attn_l[hh * DD + d];
        ar4[nt] = attn_r[hh * DD + d];
    }
#pragma unroll
    for (int mt = 0; mt < 4; mt++)
#pragma unroll
        for (int rg = 0; rg < 4; rg++) {
            float pl = 0.f, pr = 0.f;
#pragma unroll
            for (int nt = 0; nt < 4; nt++) {
                pl = fmaf(acc[mt][nt][rg], al4[nt], pl);
                pr = fmaf(acc[mt][nt][rg], ar4[nt], pr);
            }
#pragma unroll
            for (int off = 1; off < 16; off <<= 1) {
                pl += __shfl_xor(pl, off);
                pr += __shfl_xor(pr, off);
            }
            if (lr16 == 0) {            // C/D row = mt*16 + lg*4 + rg
                int row = mt * 16 + lg * 4 + rg;
                redl[w][row] = pl;
                redr[w][row] = pr;
            }
        }
    __syncthreads();
    if (t < 64) {
        float sl = redl[0][t] + redl[1][t] + redl[2][t] + redl[3][t];
        float sr = redr[0][t] + redr[1][t] + redr[2][t] + redr[3][t];
        el[hh * NTOT + row0 + t] = sl;
        er[hh * NTOT + row0 + t] = sr;
    }

    // ---- hT store: 4 consecutive s-rows per frag -> 8 B stores
    const int bdoc  = row0 >> 9;
    const int sbase = row0 & 511;
    unsigned short* hTp = hT + ((size_t)(bdoc * NH + hh) * DD) * SS;
#pragma unroll
    for (int nt = 0; nt < 4; nt++) {
        int d = w * 64 + nt * 16 + lr16;
#pragma unroll
        for (int mt = 0; mt < 4; mt++) {
            int s = sbase + mt * 16 + lg * 4;
            ushort4 u;
            u.x = f2b(acc[mt][nt][0]);
            u.y = f2b(acc[mt][nt][1]);
            u.z = f2b(acc[mt][nt][2]);
            u.w = f2b(acc[mt][nt][3]);
            *reinterpret_cast<ushort4*>(hTp + (size_t)d * SS + s) = u;
        }
    }
}

// ---------------------------------------------------------------------------
// Kernel 2: MFMA aggregation (round-3 structure, + issue-early HS loads).
// ---------------------------------------------------------------------------
__global__ __launch_bounds__(256) void k_attn(const unsigned short* __restrict__ hT,
                                              const float* __restrict__ el,
                                              const float* __restrict__ er,
                                              const float* __restrict__ bias,
                                              float* __restrict__ out) {
    __shared__ __align__(16) unsigned short PT[64 * 64];     // 8 KB, [dst][64 src]
    __shared__ __align__(16) unsigned short HS[4][64 * 64];  // 32 KB, per-wave [64 d][64 src]
    __shared__ float els[SS];
    __shared__ float ers[64], ms[64], rden[64];

    const int t    = threadIdx.x;
    const int b    = blockIdx.x >> 3;
    const int tile = blockIdx.x & 7;
    const int dst0 = tile * 64;
    const int w    = t >> 6;
    const int l    = t & 63;
    const int lr16 = l & 15;
    const int lg   = l >> 4;

    f32x4 acc[4][4];
#pragma unroll
    for (int mt = 0; mt < 4; mt++)
#pragma unroll
        for (int nt = 0; nt < 4; nt++)
#pragma unroll
            for (int r = 0; r < 4; r++) acc[mt][nt][r] = 0.f;

    for (int hh = 0; hh < NH; hh++) {
        els[t]       = el[hh * NTOT + b * SS + t];
        els[t + 256] = el[hh * NTOT + b * SS + t + 256];
        if (t < 64) ers[t] = er[hh * NTOT + b * SS + dst0 + t];
        __syncthreads();

        // softmax stats per dst (f32, 4 threads per dst)
        {
            int dd = t >> 2, q = t & 3;
            float erv = ers[dd];
            float mx = -1e30f;
            for (int s0 = q; s0 < SS; s0 += 4) {
                float x = els[s0] + erv;
                x = x > 0.f ? x : NEG * x;
                mx = fmaxf(mx, x);
            }
            mx = fmaxf(mx, __shfl_xor(mx, 1));
            mx = fmaxf(mx, __shfl_xor(mx, 2));
            float sm = 0.f;
            for (int s0 = q; s0 < SS; s0 += 4) {
                float x = els[s0] + erv;
                x = x > 0.f ? x : NEG * x;
                sm += __expf(x - mx);
            }
            sm += __shfl_xor(sm, 1);
            sm += __shfl_xor(sm, 2);
            if (q == 0) { ms[dd] = mx; rden[dd] = 1.f / sm; }
        }
        __syncthreads();

        const unsigned short* hTw = hT + ((size_t)(b * NH + hh) * DD + w * 64) * SS;
        const int q  = l & 7;      // src slot for HS staging
        const int dl = l >> 3;     // d within 8-row group

        for (int s0 = 0; s0 < SS; s0 += 64) {
            // ---- issue HS global loads EARLY (latency hides under exp work)
            uint4 hv[8];
#pragma unroll
            for (int r = 0; r < 8; r++) {
                int d = r * 8 + dl;
                hv[r] = *reinterpret_cast<const uint4*>(hTw + (size_t)d * SS + s0 + q * 8);
            }
            // ---- stage PT: thread -> (dst = t&63, 16 srcs)
            {
                int dst = t & 63;
                int sb  = (t >> 6) * 16;
                float erv = ers[dst], m = ms[dst], rd = rden[dst];
                unsigned int wb[8];
#pragma unroll
                for (int jp = 0; jp < 8; jp++) {
                    float x0 = els[s0 + sb + 2 * jp]     + erv; x0 = x0 > 0.f ? x0 : NEG * x0;
                    float x1 = els[s0 + sb + 2 * jp + 1] + erv; x1 = x1 > 0.f ? x1 : NEG * x1;
                    wb[jp] = (unsigned)f2b(__expf(x0 - m) * rd) |
                             ((unsigned)f2b(__expf(x1 - m) * rd) << 16);
                }
                int ds0   = (t >> 6) * 2;
                int slot0 = (ds0    ) ^ (dst & 7);
                int slot1 = (ds0 + 1) ^ (dst & 7);
                uint4 u0, u1;
                u0.x = wb[0]; u0.y = wb[1]; u0.z = wb[2]; u0.w = wb[3];
                u1.x = wb[4]; u1.y = wb[5]; u1.z = wb[6]; u1.w = wb[7];
                char* ptb = reinterpret_cast<char*>(PT) + dst * 128;
                *reinterpret_cast<uint4*>(ptb + slot0 * 16) = u0;
                *reinterpret_cast<uint4*>(ptb + slot1 * 16) = u1;
            }
            // ---- HS LDS writes (swizzled)
            {
                char* hsb = reinterpret_cast<char*>(&HS[w][0]);
#pragma unroll
                for (int r = 0; r < 8; r++) {
                    int d = r * 8 + dl;
                    *reinterpret_cast<uint4*>(hsb + d * 128 + ((q ^ (d & 7)) * 16)) = hv[r];
                }
            }
            __syncthreads();
            // ---- MFMA: 2 K-steps of 32
#pragma unroll
            for (int ki = 0; ki < 2; ki++) {
                int ds = ki * 4 + lg;
                bf16x8 af[4], bf[4];
                const char* ptb = reinterpret_cast<const char*>(PT);
                const char* hsb = reinterpret_cast<const char*>(&HS[w][0]);
#pragma unroll
                for (int mt = 0; mt < 4; mt++) {
                    int dst = mt * 16 + lr16;
                    af[mt] = *reinterpret_cast<const bf16x8*>(ptb + dst * 128 + ((ds ^ (dst & 7)) * 16));
                }
#pragma unroll
                for (int nt = 0; nt < 4; nt++) {
                    int d = nt * 16 + lr16;
                    bf[nt] = *reinterpret_cast<const bf16x8*>(hsb + d * 128 + ((ds ^ (d & 7)) * 16));
                }
#pragma unroll
                for (int mt = 0; mt < 4; mt++)
#pragma unroll
                    for (int nt = 0; nt < 4; nt++)
                        acc[mt][nt] = __builtin_amdgcn_mfma_f32_16x16x32_bf16(
                            af[mt], bf[nt], acc[mt][nt], 0, 0, 0);
            }
            __syncthreads();
        }
    }

    // epilogue: out = 0.25*(sum_h acc + sum_h bias); C/D: col=l&15, row=lg*4+reg
    float bs[4];
#pragma unroll
    for (int nt = 0; nt < 4; nt++) {
        int d = w * 64 + nt * 16 + lr16;
        float s = 0.f;
        for (int h2 = 0; h2 < NH; h2++) s += bias[h2 * DD + d];
        bs[nt] = s;
    }
#pragma unroll
    for (int mt = 0; mt < 4; mt++) {
        int rowb = b * SS + dst0 + mt * 16 + lg * 4;
#pragma unroll
        for (int nt = 0; nt < 4; nt++) {
            int d = w * 64 + nt * 16 + lr16;
#pragma unroll
            for (int rg = 0; rg < 4; rg++)
                out[(size_t)(rowb + rg) * DD + d] = 0.25f * (acc[mt][nt][rg] + bs[nt]);
        }
    }
}

// ---------------------------------------------------------------------------
extern "C" void kernel_launch(void* const* d_in, const int* in_sizes, int n_in,
                              void* d_out, int out_size, void* d_ws, size_t ws_size,
                              hipStream_t stream) {
    const float* X      = (const float*)d_in[0];  // sent_feature [32768,256]
    const float* W      = (const float*)d_in[1];  // [256,1024]
    const float* attn_l = (const float*)d_in[2];  // [4,256]
    const float* attn_r = (const float*)d_in[3];  // [4,256]
    const float* bias   = (const float*)d_in[4];  // [1024]
    // d_in[5] = num_docs (constant 64, baked in)

    unsigned short* hT = (unsigned short*)d_ws;                    // 64 MiB bf16 hT[b][h][d][s]
    float* elp = (float*)((char*)d_ws + (size_t)NTOT * HF * 2);    // 512 KB
    float* erp = elp + (size_t)NH * NTOT;                          // 512 KB
    unsigned short* WTp = (unsigned short*)(erp + (size_t)NH * NTOT); // 512 KB
    float* outp = (float*)d_out;

    k_wt<<<64, 256, 0, stream>>>(W, WTp);
    k_fc<<<2048, 256, 0, stream>>>(X, WTp, attn_l, attn_r, hT, elp, erp);
    k_attn<<<NDOCS * 8, 256, 0, stream>>>(hT, elp, erp, bias, outp);
}

// Round 6
// 303.337 us; speedup vs baseline: 3.3224x; 1.0554x over previous
//
#include <hip/hip_runtime.h>
#include <hip/hip_bf16.h>

// Problem constants (from reference setup_inputs)
#define NDOCS 64
#define SS    512            // sentences per doc
#define FIN   256            // HIDDEN (input features)
#define NH    4              // heads
#define DD    256            // per-head out feats
#define NTOT  (NDOCS*SS)     // 32768 rows
#define HF    (NH*DD)        // 1024
#define NEG   0.2f
#define LDA   264            // Ald row stride in shorts

typedef __attribute__((ext_vector_type(8))) short bf16x8;   // 8 bf16 = 4 VGPRs
typedef __attribute__((ext_vector_type(4))) float f32x4;    // MFMA 16x16 acc

__device__ __forceinline__ unsigned short f2b(float x) {
    __hip_bfloat16 b = __float2bfloat16(x);
    return *reinterpret_cast<unsigned short*>(&b);
}
__device__ __forceinline__ unsigned pk2(float a, float b) {
    return (unsigned)f2b(a) | ((unsigned)f2b(b) << 16);
}

// LDS-only barrier: waits ds ops but leaves global (vmcnt) loads in flight (T4).
#define BARLDS() do { asm volatile("s_waitcnt lgkmcnt(0)" ::: "memory"); \
                      __builtin_amdgcn_s_barrier(); } while (0)

// ---------------------------------------------------------------------------
// Kernel 0: WT[n][k] = bf16(W[k][n])  (1024 x 256, 0.5 MB)
// ---------------------------------------------------------------------------
__global__ __launch_bounds__(256) void k_wt(const float* __restrict__ W,
                                            unsigned short* __restrict__ WT) {
    int n  = blockIdx.x * 16 + (threadIdx.x & 15);
    int k0 = threadIdx.x >> 4;
#pragma unroll
    for (int i = 0; i < 16; i++) {
        int k = i * 16 + k0;
        WT[(size_t)n * FIN + k] = f2b(W[(size_t)k * HF + n]);
    }
}

// ---------------------------------------------------------------------------
// Kernel 1 (MFMA): h = X @ W. 64 rows x 256 cols (one head) per block.
// Changed this round: hT store goes through a swizzled LDS bounce so global
// stores are 128B-contiguous per d-row (full 64B lines), not 8B scatter.
// ---------------------------------------------------------------------------
__global__ __launch_bounds__(256) void k_fc(const float* __restrict__ X,
                                            const unsigned short* __restrict__ WT,
                                            const float* __restrict__ attn_l,
                                            const float* __restrict__ attn_r,
                                            unsigned short* __restrict__ hT,
                                            float* __restrict__ el,
                                            float* __restrict__ er) {
    __shared__ __align__(16) unsigned short Ald[64 * LDA];   // 33 KB (reused as HL)
    __shared__ float redl[4][64], redr[4][64];               // 2 KB

    const int t    = threadIdx.x;
    const int mt64 = blockIdx.x >> 2;
    const int hh   = blockIdx.x & 3;
    const int row0 = mt64 * 64;
    const int w    = t >> 6;
    const int l    = t & 63;
    const int lr16 = l & 15;
    const int lg   = l >> 4;

    // ---- stage X[row0..+64][0..256) f32 -> bf16 LDS
    {
        const int c4   = (t & 63) * 4;
        const int rsub = t >> 6;
#pragma unroll
        for (int i = 0; i < 16; i++) {
            int r = i * 4 + rsub;
            float4 v = *reinterpret_cast<const float4*>(X + (size_t)(row0 + r) * FIN + c4);
            uint2 uu;
            uu.x = pk2(v.x, v.y);
            uu.y = pk2(v.z, v.w);
            *reinterpret_cast<uint2*>(&Ald[r * LDA + c4]) = uu;
        }
    }
    __syncthreads();

    f32x4 acc[4][4];
#pragma unroll
    for (int mt = 0; mt < 4; mt++)
#pragma unroll
        for (int nt = 0; nt < 4; nt++)
#pragma unroll
            for (int rg = 0; rg < 4; rg++) acc[mt][nt][rg] = 0.f;

    const unsigned short* wtb = WT + (size_t)(hh * DD + w * 64) * FIN;

#pragma unroll
    for (int kc = 0; kc < 8; kc++) {
        bf16x8 af[4], bv[4];
#pragma unroll
        for (int mt = 0; mt < 4; mt++)
            af[mt] = *reinterpret_cast<const bf16x8*>(
                &Ald[(mt * 16 + lr16) * LDA + kc * 32 + lg * 8]);
#pragma unroll
        for (int nt = 0; nt < 4; nt++)
            bv[nt] = *reinterpret_cast<const bf16x8*>(
                wtb + (size_t)(nt * 16 + lr16) * FIN + kc * 32 + lg * 8);
#pragma unroll
        for (int mt = 0; mt < 4; mt++)
#pragma unroll
            for (int nt = 0; nt < 4; nt++)
                acc[mt][nt] = __builtin_amdgcn_mfma_f32_16x16x32_bf16(
                    af[mt], bv[nt], acc[mt][nt], 0, 0, 0);
    }

    // ---- el/er reduce (unchanged)
    float al4[4], ar4[4];
#pragma unroll
    for (int nt = 0; nt < 4; nt++) {
        int d = w * 64 + nt * 16 + lr16;
        al4[nt] = attn_l[hh * DD + d];
        ar4[nt] = attn_r[hh * DD + d];
    }
#pragma unroll
    for (int mt = 0; mt < 4; mt++)
#pragma unroll
        for (int rg = 0; rg < 4; rg++) {
            float pl = 0.f, pr = 0.f;
#pragma unroll
            for (int nt = 0; nt < 4; nt++) {
                pl = fmaf(acc[mt][nt][rg], al4[nt], pl);
                pr = fmaf(acc[mt][nt][rg], ar4[nt], pr);
            }
#pragma unroll
            for (int off = 1; off < 16; off <<= 1) {
                pl += __shfl_xor(pl, off);
                pr += __shfl_xor(pr, off);
            }
            if (lr16 == 0) {
                int row = mt * 16 + lg * 4 + rg;
                redl[w][row] = pl;
                redr[w][row] = pr;
            }
        }
    __syncthreads();   // guards redl/redr AND all Ald K-loop reads
    if (t < 64) {
        float sl = redl[0][t] + redl[1][t] + redl[2][t] + redl[3][t];
        float sr = redr[0][t] + redr[1][t] + redr[2][t] + redr[3][t];
        el[hh * NTOT + row0 + t] = sl;
        er[hh * NTOT + row0 + t] = sr;
    }

    // ---- hT store via swizzled LDS bounce (Ald reused as HL[256][64] bf16).
    // Write side: 8B unit u_w = mt*4+lg at physical p = u_w ^ ((d&7)<<1)
    // (16 consecutive-d lanes -> 8 distinct bank-pairs, 2-way = free).
    {
        unsigned short* HL = Ald;  // 32 KB needed, 33 KB available
#pragma unroll
        for (int nt = 0; nt < 4; nt++) {
            int d = w * 64 + nt * 16 + lr16;
#pragma unroll
            for (int mt = 0; mt < 4; mt++) {
                int p = (mt * 4 + lg) ^ ((d & 7) << 1);
                ushort4 u;
                u.x = f2b(acc[mt][nt][0]);
                u.y = f2b(acc[mt][nt][1]);
                u.z = f2b(acc[mt][nt][2]);
                u.w = f2b(acc[mt][nt][3]);
                *reinterpret_cast<ushort4*>(HL + d * 64 + p * 4) = u;
            }
        }
        __syncthreads();
        // Flush: lane -> (d = r*32 + t>>3, chunk c = t&7); 8 lanes cover one
        // 128B d-row contiguously -> 2 full 64B lines per row.
        const int bdoc  = row0 >> 9;
        const int sbase = row0 & 511;
        unsigned short* hTp = hT + ((size_t)(bdoc * NH + hh) * DD) * SS;
        const int dl = t >> 3, c = t & 7;
#pragma unroll
        for (int r = 0; r < 8; r++) {
            int d = r * 32 + dl;
            uint4 v = *reinterpret_cast<const uint4*>(HL + d * 64 + ((c ^ (d & 7)) << 3));
            *reinterpret_cast<uint4*>(hTp + (size_t)d * SS + sbase + c * 8) = v;
        }
    }
}

// ---------------------------------------------------------------------------
// Kernel 2: MFMA aggregation, restructured:
//  - NO softmax max/sum passes: PT holds unnormalized exp(lrelu(el+er))
//    (|x| <~ 12 -> exp <= 2e5, f32/bf16 safe); denominator accumulated
//    during staging; rden applied per-head to the accumulator (acch->master).
//  - HS double-buffered; per-chunk barriers are lgkmcnt-only so prefetch
//    global loads stay in flight across them (T4).
//  - Doc-affine XCD swizzle: physical wgid = tile*64 + doc  =>  all 8 tiles
//    of a doc share wgid mod 8 (same XCD L2 holds the doc's 1 MB hT).
// ---------------------------------------------------------------------------
__global__ __launch_bounds__(256, 2) void k_attn(const unsigned short* __restrict__ hT,
                                                 const float* __restrict__ el,
                                                 const float* __restrict__ er,
                                                 const float* __restrict__ bias,
                                                 float* __restrict__ out) {
    __shared__ __align__(16) unsigned short PT[64 * 64];        // 8 KB
    __shared__ __align__(16) unsigned short HS[2][4][64 * 64];  // 64 KB (dbuf)
    __shared__ float els[SS];                                   // 2 KB
    __shared__ float ers[64];
    __shared__ float esumL[4][64];
    __shared__ float rdenL[64];

    const int t    = threadIdx.x;
    const int b    = blockIdx.x & 63;   // doc  (XCD-affine decode)
    const int tile = blockIdx.x >> 6;   // dst tile
    const int dst0 = tile * 64;
    const int w    = t >> 6;
    const int l    = t & 63;
    const int lr16 = l & 15;
    const int lg   = l >> 4;
    const int q    = l & 7;             // HS staging src slot
    const int dl   = l >> 3;            // HS staging d sub-row
    const int dstT = t & 63;            // PT staging dst
    const int sbT  = (t >> 6) * 16;     // PT staging src slice

    f32x4 master[4][4];
#pragma unroll
    for (int mt = 0; mt < 4; mt++)
#pragma unroll
        for (int nt = 0; nt < 4; nt++)
#pragma unroll
            for (int r = 0; r < 4; r++) master[mt][nt][r] = 0.f;

    for (int hh = 0; hh < NH; hh++) {
        const unsigned short* hTw = hT + ((size_t)(b * NH + hh) * DD + w * 64) * SS;

        // issue chunk-0 HS loads first (latency overlaps els staging+barrier)
        uint4 hv[8];
#pragma unroll
        for (int r = 0; r < 8; r++)
            hv[r] = *reinterpret_cast<const uint4*>(hTw + (size_t)(r * 8 + dl) * SS + q * 8);

        els[t]       = el[hh * NTOT + b * SS + t];
        els[t + 256] = el[hh * NTOT + b * SS + t + 256];
        if (t < 64) ers[t] = er[hh * NTOT + b * SS + dst0 + t];
        BARLDS();

        const float erv = ers[dstT];
        float myesum = 0.f;
        f32x4 acch[4][4];
#pragma unroll
        for (int mt = 0; mt < 4; mt++)
#pragma unroll
            for (int nt = 0; nt < 4; nt++)
#pragma unroll
                for (int r = 0; r < 4; r++) acch[mt][nt][r] = 0.f;

        for (int i = 0; i < 8; i++) {
            const int s0  = i * 64;
            const int cur = i & 1;
            // (a) unnormalized exps for chunk i + denominator accumulation
            unsigned wb[8];
#pragma unroll
            for (int jp = 0; jp < 8; jp++) {
                float x0 = els[s0 + sbT + 2 * jp]     + erv; x0 = x0 > 0.f ? x0 : NEG * x0;
                float x1 = els[s0 + sbT + 2 * jp + 1] + erv; x1 = x1 > 0.f ? x1 : NEG * x1;
                float e0 = __expf(x0), e1 = __expf(x1);
                myesum += e0 + e1;
                wb[jp] = pk2(e0, e1);
            }
            // (b) previous MFMA done reading PT / HS[cur] before overwrite
            BARLDS();
            // (c) write PT + HS[cur]; then issue next chunk's loads
            {
                int ds0   = (t >> 6) * 2;
                int slot0 = (ds0    ) ^ (dstT & 7);
                int slot1 = (ds0 + 1) ^ (dstT & 7);
                uint4 u0, u1;
                u0.x = wb[0]; u0.y = wb[1]; u0.z = wb[2]; u0.w = wb[3];
                u1.x = wb[4]; u1.y = wb[5]; u1.z = wb[6]; u1.w = wb[7];
                char* ptb = reinterpret_cast<char*>(PT) + dstT * 128;
                *reinterpret_cast<uint4*>(ptb + slot0 * 16) = u0;
                *reinterpret_cast<uint4*>(ptb + slot1 * 16) = u1;
                char* hsb = reinterpret_cast<char*>(&HS[cur][w][0]);
#pragma unroll
                for (int r = 0; r < 8; r++) {
                    int d = r * 8 + dl;
                    *reinterpret_cast<uint4*>(hsb + d * 128 + ((q ^ (d & 7)) * 16)) = hv[r];
                }
                if (i < 7) {
#pragma unroll
                    for (int r = 0; r < 8; r++)
                        hv[r] = *reinterpret_cast<const uint4*>(
                            hTw + (size_t)(r * 8 + dl) * SS + (s0 + 64) + q * 8);
                }
            }
            // (d) staged data visible; prefetch stays in flight (vmcnt untouched)
            BARLDS();
            // (e) MFMA: 2 K-steps of 32
            const char* ptb = reinterpret_cast<const char*>(PT);
            const char* hsb = reinterpret_cast<const char*>(&HS[cur][w][0]);
#pragma unroll
            for (int ki = 0; ki < 2; ki++) {
                int ds = ki * 4 + lg;
                bf16x8 af[4], bf[4];
#pragma unroll
                for (int mt = 0; mt < 4; mt++) {
                    int dst = mt * 16 + lr16;
                    af[mt] = *reinterpret_cast<const bf16x8*>(ptb + dst * 128 + ((ds ^ (dst & 7)) * 16));
                }
#pragma unroll
                for (int nt = 0; nt < 4; nt++) {
                    int d = nt * 16 + lr16;
                    bf[nt] = *reinterpret_cast<const bf16x8*>(hsb + d * 128 + ((ds ^ (d & 7)) * 16));
                }
#pragma unroll
                for (int mt = 0; mt < 4; mt++)
#pragma unroll
                    for (int nt = 0; nt < 4; nt++)
                        acch[mt][nt] = __builtin_amdgcn_mfma_f32_16x16x32_bf16(
                            af[mt], bf[nt], acch[mt][nt], 0, 0, 0);
            }
        }

        // ---- per-head normalization: rden[dst] = 1/sum_s e, master += rden*acch
        esumL[w][l] = myesum;            // lane l == dstT, slice w
        __syncthreads();
        if (t < 64)
            rdenL[t] = 1.f / (esumL[0][t] + esumL[1][t] + esumL[2][t] + esumL[3][t]);
        __syncthreads();
#pragma unroll
        for (int mt = 0; mt < 4; mt++)
#pragma unroll
            for (int rg = 0; rg < 4; rg++) {
                float rd = rdenL[mt * 16 + lg * 4 + rg];
#pragma unroll
                for (int nt = 0; nt < 4; nt++)
                    master[mt][nt][rg] = fmaf(rd, acch[mt][nt][rg], master[mt][nt][rg]);
            }
    }

    // epilogue: out = 0.25*(master + sum_h bias); C/D: col=l&15, row=lg*4+reg
    float bs[4];
#pragma unroll
    for (int nt = 0; nt < 4; nt++) {
        int d = w * 64 + nt * 16 + lr16;
        float s = 0.f;
        for (int h2 = 0; h2 < NH; h2++) s += bias[h2 * DD + d];
        bs[nt] = s;
    }
#pragma unroll
    for (int mt = 0; mt < 4; mt++) {
        int rowb = b * SS + dst0 + mt * 16 + lg * 4;
#pragma unroll
        for (int nt = 0; nt < 4; nt++) {
            int d = w * 64 + nt * 16 + lr16;
#pragma unroll
            for (int rg = 0; rg < 4; rg++)
                out[(size_t)(rowb + rg) * DD + d] = 0.25f * (master[mt][nt][rg] + bs[nt]);
        }
    }
}

// ---------------------------------------------------------------------------
extern "C" void kernel_launch(void* const* d_in, const int* in_sizes, int n_in,
                              void* d_out, int out_size, void* d_ws, size_t ws_size,
                              hipStream_t stream) {
    const float* X      = (const float*)d_in[0];
    const float* W      = (const float*)d_in[1];
    const float* attn_l = (const float*)d_in[2];
    const float* attn_r = (const float*)d_in[3];
    const float* bias   = (const float*)d_in[4];
    // d_in[5] = num_docs (constant 64, baked in)

    unsigned short* hT = (unsigned short*)d_ws;                       // 64 MiB
    float* elp = (float*)((char*)d_ws + (size_t)NTOT * HF * 2);       // 512 KB
    float* erp = elp + (size_t)NH * NTOT;                             // 512 KB
    unsigned short* WTp = (unsigned short*)(erp + (size_t)NH * NTOT); // 512 KB
    float* outp = (float*)d_out;

    k_wt<<<64, 256, 0, stream>>>(W, WTp);
    k_fc<<<2048, 256, 0, stream>>>(X, WTp, attn_l, attn_r, hT, elp, erp);
    k_attn<<<NDOCS * 8, 256, 0, stream>>>(hT, elp, erp, bias, outp);
}

// Round 7
// 231.107 us; speedup vs baseline: 4.3608x; 1.3125x over previous
//
#include <hip/hip_runtime.h>
#include <hip/hip_bf16.h>

// Problem constants (from reference setup_inputs)
#define NDOCS 64
#define SS    512            // sentences per doc
#define FIN   256            // HIDDEN (input features)
#define NH    4              // heads
#define DD    256            // per-head out feats
#define NTOT  (NDOCS*SS)     // 32768 rows
#define HF    (NH*DD)        // 1024
#define NEG   0.2f
#define LDA   264            // Ald row stride in shorts

typedef __attribute__((ext_vector_type(8))) short bf16x8;   // 8 bf16 = 4 VGPRs
typedef __attribute__((ext_vector_type(4))) float f32x4;    // MFMA 16x16 acc

__device__ __forceinline__ unsigned short f2b(float x) {
    __hip_bfloat16 b = __float2bfloat16(x);
    return *reinterpret_cast<unsigned short*>(&b);
}
__device__ __forceinline__ unsigned pk2(float a, float b) {
    return (unsigned)f2b(a) | ((unsigned)f2b(b) << 16);
}
__device__ __forceinline__ float blo(unsigned u) {   // low bf16 -> f32
    unsigned v = u << 16; return *reinterpret_cast<float*>(&v);
}
__device__ __forceinline__ float bhi(unsigned u) {   // high bf16 -> f32
    unsigned v = u & 0xffff0000u; return *reinterpret_cast<float*>(&v);
}

// LDS-only barrier: waits ds ops but leaves global (vmcnt) loads in flight (T4).
#define BARLDS() do { asm volatile("s_waitcnt lgkmcnt(0)" ::: "memory"); \
                      __builtin_amdgcn_s_barrier(); } while (0)

// ---------------------------------------------------------------------------
// Kernel 0: WT[n][k] = bf16(W[k][n])  (1024 x 256, 0.5 MB)
// ---------------------------------------------------------------------------
__global__ __launch_bounds__(256) void k_wt(const float* __restrict__ W,
                                            unsigned short* __restrict__ WT) {
    int n  = blockIdx.x * 16 + (threadIdx.x & 15);
    int k0 = threadIdx.x >> 4;
#pragma unroll
    for (int i = 0; i < 16; i++) {
        int k = i * 16 + k0;
        WT[(size_t)n * FIN + k] = f2b(W[(size_t)k * HF + n]);
    }
}

// ---------------------------------------------------------------------------
// Kernel 1 (MFMA): h = X @ W — UNCHANGED from round 6 (single-variable rule;
// counters will surface next round once k_attn drops below it).
// ---------------------------------------------------------------------------
__global__ __launch_bounds__(256) void k_fc(const float* __restrict__ X,
                                            const unsigned short* __restrict__ WT,
                                            const float* __restrict__ attn_l,
                                            const float* __restrict__ attn_r,
                                            unsigned short* __restrict__ hT,
                                            float* __restrict__ el,
                                            float* __restrict__ er) {
    __shared__ __align__(16) unsigned short Ald[64 * LDA];   // 33 KB (reused as HL)
    __shared__ float redl[4][64], redr[4][64];               // 2 KB

    const int t    = threadIdx.x;
    const int mt64 = blockIdx.x >> 2;
    const int hh   = blockIdx.x & 3;
    const int row0 = mt64 * 64;
    const int w    = t >> 6;
    const int l    = t & 63;
    const int lr16 = l & 15;
    const int lg   = l >> 4;

    {
        const int c4   = (t & 63) * 4;
        const int rsub = t >> 6;
#pragma unroll
        for (int i = 0; i < 16; i++) {
            int r = i * 4 + rsub;
            float4 v = *reinterpret_cast<const float4*>(X + (size_t)(row0 + r) * FIN + c4);
            uint2 uu;
            uu.x = pk2(v.x, v.y);
            uu.y = pk2(v.z, v.w);
            *reinterpret_cast<uint2*>(&Ald[r * LDA + c4]) = uu;
        }
    }
    __syncthreads();

    f32x4 acc[4][4];
#pragma unroll
    for (int mt = 0; mt < 4; mt++)
#pragma unroll
        for (int nt = 0; nt < 4; nt++)
#pragma unroll
            for (int rg = 0; rg < 4; rg++) acc[mt][nt][rg] = 0.f;

    const unsigned short* wtb = WT + (size_t)(hh * DD + w * 64) * FIN;

#pragma unroll
    for (int kc = 0; kc < 8; kc++) {
        bf16x8 af[4], bv[4];
#pragma unroll
        for (int mt = 0; mt < 4; mt++)
            af[mt] = *reinterpret_cast<const bf16x8*>(
                &Ald[(mt * 16 + lr16) * LDA + kc * 32 + lg * 8]);
#pragma unroll
        for (int nt = 0; nt < 4; nt++)
            bv[nt] = *reinterpret_cast<const bf16x8*>(
                wtb + (size_t)(nt * 16 + lr16) * FIN + kc * 32 + lg * 8);
#pragma unroll
        for (int mt = 0; mt < 4; mt++)
#pragma unroll
            for (int nt = 0; nt < 4; nt++)
                acc[mt][nt] = __builtin_amdgcn_mfma_f32_16x16x32_bf16(
                    af[mt], bv[nt], acc[mt][nt], 0, 0, 0);
    }

    float al4[4], ar4[4];
#pragma unroll
    for (int nt = 0; nt < 4; nt++) {
        int d = w * 64 + nt * 16 + lr16;
        al4[nt] = attn_l[hh * DD + d];
        ar4[nt] = attn_r[hh * DD + d];
    }
#pragma unroll
    for (int mt = 0; mt < 4; mt++)
#pragma unroll
        for (int rg = 0; rg < 4; rg++) {
            float pl = 0.f, pr = 0.f;
#pragma unroll
            for (int nt = 0; nt < 4; nt++) {
                pl = fmaf(acc[mt][nt][rg], al4[nt], pl);
                pr = fmaf(acc[mt][nt][rg], ar4[nt], pr);
            }
#pragma unroll
            for (int off = 1; off < 16; off <<= 1) {
                pl += __shfl_xor(pl, off);
                pr += __shfl_xor(pr, off);
            }
            if (lr16 == 0) {
                int row = mt * 16 + lg * 4 + rg;
                redl[w][row] = pl;
                redr[w][row] = pr;
            }
        }
    __syncthreads();
    if (t < 64) {
        float sl = redl[0][t] + redl[1][t] + redl[2][t] + redl[3][t];
        float sr = redr[0][t] + redr[1][t] + redr[2][t] + redr[3][t];
        el[hh * NTOT + row0 + t] = sl;
        er[hh * NTOT + row0 + t] = sr;
    }

    {
        unsigned short* HL = Ald;  // 32 KB reuse
#pragma unroll
        for (int nt = 0; nt < 4; nt++) {
            int d = w * 64 + nt * 16 + lr16;
#pragma unroll
            for (int mt = 0; mt < 4; mt++) {
                int p = (mt * 4 + lg) ^ ((d & 7) << 1);
                ushort4 u;
                u.x = f2b(acc[mt][nt][0]);
                u.y = f2b(acc[mt][nt][1]);
                u.z = f2b(acc[mt][nt][2]);
                u.w = f2b(acc[mt][nt][3]);
                *reinterpret_cast<ushort4*>(HL + d * 64 + p * 4) = u;
            }
        }
        __syncthreads();
        const int bdoc  = row0 >> 9;
        const int sbase = row0 & 511;
        unsigned short* hTp = hT + ((size_t)(bdoc * NH + hh) * DD) * SS;
        const int dl = t >> 3, c = t & 7;
#pragma unroll
        for (int r = 0; r < 8; r++) {
            int d = r * 32 + dl;
            uint4 v = *reinterpret_cast<const uint4*>(HL + d * 64 + ((c ^ (d & 7)) << 3));
            *reinterpret_cast<uint4*>(hTp + (size_t)d * SS + sbase + c * 8) = v;
        }
    }
}

// ---------------------------------------------------------------------------
// Kernel 2: MFMA aggregation, restructured (round 7):
//  - NO HS LDS staging: B-frags loaded DIRECTLY from global hT (layout
//    matches fragment exactly; data is XCD-L2-resident; zero intra-block
//    reuse made LDS a pure overhead). Next chunk's frags prefetched into
//    registers before the barrier (loads fly across lgkmcnt-only barrier).
//  - Per-head exps computed ONCE into 64 packed VGPRs (ecache) + summed ->
//    rden known BEFORE staging -> PT holds NORMALIZED P -> single master
//    accumulator (no acch: -64 VGPR, removes suspected spill traffic).
//  - PT double-buffered (2x8 KB), ONE lgkmcnt-only barrier per chunk.
// ---------------------------------------------------------------------------
__global__ __launch_bounds__(256) void k_attn(const unsigned short* __restrict__ hT,
                                              const float* __restrict__ el,
                                              const float* __restrict__ er,
                                              const float* __restrict__ bias,
                                              float* __restrict__ out) {
    __shared__ __align__(16) unsigned short PT[2][64 * 64];  // 16 KB dbuf
    __shared__ float els[SS];                                // 2 KB
    __shared__ float ers[64];
    __shared__ float esumL[4][64];
    __shared__ float rdenL[64];

    const int t    = threadIdx.x;
    const int b    = blockIdx.x & 63;   // doc (XCD-affine decode)
    const int tile = blockIdx.x >> 6;   // dst tile
    const int dst0 = tile * 64;
    const int w    = t >> 6;
    const int l    = t & 63;
    const int lr16 = l & 15;
    const int lg   = l >> 4;
    const int dstT = t & 63;            // PT staging dst
    const int sbT  = (t >> 6) * 16;     // PT staging src slice

    f32x4 master[4][4];
#pragma unroll
    for (int mt = 0; mt < 4; mt++)
#pragma unroll
        for (int nt = 0; nt < 4; nt++)
#pragma unroll
            for (int r = 0; r < 4; r++) master[mt][nt][r] = 0.f;

    for (int hh = 0; hh < NH; hh++) {
        const unsigned short* hTw = hT + ((size_t)(b * NH + hh) * DD + w * 64) * SS;

        els[t]       = el[hh * NTOT + b * SS + t];
        els[t + 256] = el[hh * NTOT + b * SS + t + 256];
        if (t < 64) ers[t] = er[hh * NTOT + b * SS + dst0 + t];
        BARLDS();

        // ---- exp phase: all 512 exps for (dstT), packed bf16 in regs
        const float erv = ers[dstT];
        float myesum = 0.f;
        unsigned ecache[8][8];
#pragma unroll
        for (int c = 0; c < 8; c++)
#pragma unroll
            for (int jp = 0; jp < 8; jp++) {
                float x0 = els[c * 64 + sbT + 2 * jp]     + erv; x0 = x0 > 0.f ? x0 : NEG * x0;
                float x1 = els[c * 64 + sbT + 2 * jp + 1] + erv; x1 = x1 > 0.f ? x1 : NEG * x1;
                float e0 = __expf(x0), e1 = __expf(x1);
                myesum += e0 + e1;
                ecache[c][jp] = pk2(e0, e1);
            }
        esumL[w][dstT] = myesum;
        __syncthreads();
        if (t < 64)
            rdenL[t] = 1.f / (esumL[0][t] + esumL[1][t] + esumL[2][t] + esumL[3][t]);
        __syncthreads();
        const float rd = rdenL[dstT];

        // ---- preload chunk-0 B-frags from global (registers)
        bf16x8 bcur[4][2];
#pragma unroll
        for (int nt = 0; nt < 4; nt++)
#pragma unroll
            for (int ki = 0; ki < 2; ki++)
                bcur[nt][ki] = *reinterpret_cast<const bf16x8*>(
                    hTw + (size_t)(nt * 16 + lr16) * SS + (ki * 4 + lg) * 8);

#pragma unroll
        for (int c = 0; c < 8; c++) {
            const int cur = c & 1;
            // (a) write PT[cur]: normalized P from cached exps
            {
                unsigned wb[8];
#pragma unroll
                for (int jp = 0; jp < 8; jp++)
                    wb[jp] = pk2(blo(ecache[c][jp]) * rd, bhi(ecache[c][jp]) * rd);
                int ds0   = (t >> 6) * 2;
                int slot0 = (ds0    ) ^ (dstT & 7);
                int slot1 = (ds0 + 1) ^ (dstT & 7);
                uint4 u0, u1;
                u0.x = wb[0]; u0.y = wb[1]; u0.z = wb[2]; u0.w = wb[3];
                u1.x = wb[4]; u1.y = wb[5]; u1.z = wb[6]; u1.w = wb[7];
                char* ptb = reinterpret_cast<char*>(&PT[cur][0]) + dstT * 128;
                *reinterpret_cast<uint4*>(ptb + slot0 * 16) = u0;
                *reinterpret_cast<uint4*>(ptb + slot1 * 16) = u1;
            }
            // (b) prefetch next chunk's B-frags (stay in flight across barrier)
            bf16x8 bnxt[4][2];
            if (c < 7) {
#pragma unroll
                for (int nt = 0; nt < 4; nt++)
#pragma unroll
                    for (int ki = 0; ki < 2; ki++)
                        bnxt[nt][ki] = *reinterpret_cast<const bf16x8*>(
                            hTw + (size_t)(nt * 16 + lr16) * SS + (c + 1) * 64 + (ki * 4 + lg) * 8);
            }
            // (c) PT[cur] visible to all waves; global prefetch NOT drained
            BARLDS();
            // (d) MFMA: A from PT[cur] (LDS), B from registers
            const char* ptb = reinterpret_cast<const char*>(&PT[cur][0]);
#pragma unroll
            for (int ki = 0; ki < 2; ki++) {
                int ds = ki * 4 + lg;
                bf16x8 af[4];
#pragma unroll
                for (int mt = 0; mt < 4; mt++) {
                    int dst = mt * 16 + lr16;
                    af[mt] = *reinterpret_cast<const bf16x8*>(ptb + dst * 128 + ((ds ^ (dst & 7)) * 16));
                }
#pragma unroll
                for (int mt = 0; mt < 4; mt++)
#pragma unroll
                    for (int nt = 0; nt < 4; nt++)
                        master[mt][nt] = __builtin_amdgcn_mfma_f32_16x16x32_bf16(
                            af[mt], bcur[nt][ki], master[mt][nt], 0, 0, 0);
            }
            if (c < 7) {
#pragma unroll
                for (int nt = 0; nt < 4; nt++)
#pragma unroll
                    for (int ki = 0; ki < 2; ki++) bcur[nt][ki] = bnxt[nt][ki];
            }
        }
        __syncthreads();   // PT/els quiesced before next head's rewrite
    }

    // epilogue: out = 0.25*(master + sum_h bias); C/D: col=l&15, row=lg*4+reg
    float bs[4];
#pragma unroll
    for (int nt = 0; nt < 4; nt++) {
        int d = w * 64 + nt * 16 + lr16;
        float s = 0.f;
        for (int h2 = 0; h2 < NH; h2++) s += bias[h2 * DD + d];
        bs[nt] = s;
    }
#pragma unroll
    for (int mt = 0; mt < 4; mt++) {
        int rowb = b * SS + dst0 + mt * 16 + lg * 4;
#pragma unroll
        for (int nt = 0; nt < 4; nt++) {
            int d = w * 64 + nt * 16 + lr16;
#pragma unroll
            for (int rg = 0; rg < 4; rg++)
                out[(size_t)(rowb + rg) * DD + d] = 0.25f * (master[mt][nt][rg] + bs[nt]);
        }
    }
}

// ---------------------------------------------------------------------------
extern "C" void kernel_launch(void* const* d_in, const int* in_sizes, int n_in,
                              void* d_out, int out_size, void* d_ws, size_t ws_size,
                              hipStream_t stream) {
    const float* X      = (const float*)d_in[0];
    const float* W      = (const float*)d_in[1];
    const float* attn_l = (const float*)d_in[2];
    const float* attn_r = (const float*)d_in[3];
    const float* bias   = (const float*)d_in[4];
    // d_in[5] = num_docs (constant 64, baked in)

    unsigned short* hT = (unsigned short*)d_ws;                       // 64 MiB
    float* elp = (float*)((char*)d_ws + (size_t)NTOT * HF * 2);       // 512 KB
    float* erp = elp + (size_t)NH * NTOT;                             // 512 KB
    unsigned short* WTp = (unsigned short*)(erp + (size_t)NH * NTOT); // 512 KB
    float* outp = (float*)d_out;

    k_wt<<<64, 256, 0, stream>>>(W, WTp);
    k_fc<<<2048, 256, 0, stream>>>(X, WTp, attn_l, attn_r, hT, elp, erp);
    k_attn<<<NDOCS * 8, 256, 0, stream>>>(hT, elp, erp, bias, outp);
}